// Round 2
// baseline (192.664 us; speedup 1.0000x reference)
//
#include <hip/hip_runtime.h>
#include <stdint.h>

// S4Block: out = xln + FIR(Khat, xln) + D_re * cumsum(xln), xln = LN(x @ W^T + b)
// ws layout: [0,128KB) Khat ; [128KB, +32MB) X_bf16 ; then W_bf16 (2MB). y lives in d_out.

typedef __attribute__((ext_vector_type(8))) short short8;           // 8 bf16 MFMA frag
typedef __attribute__((ext_vector_type(8))) unsigned short ushort8; // 16B store
typedef __attribute__((ext_vector_type(4))) float f32x4;
typedef unsigned short ushort;

#define L_SEQ 2048
#define DM    1024
#define TT    32     // FIR taps (|A|^32 ~ 1e-14)
#define MT    16     // channels per SSM block
#define TC    256    // timesteps per SSM chunk

__device__ __forceinline__ unsigned short f2bf(float f) {
  uint32_t u = __builtin_bit_cast(uint32_t, f);
  u += 0x7FFFu + ((u >> 16) & 1u);   // RNE
  return (unsigned short)(u >> 16);
}

__device__ __forceinline__ void gload16(const void* g, void* lds) {
  __builtin_amdgcn_global_load_lds(
      (const __attribute__((address_space(1))) uint32_t*)g,
      (__attribute__((address_space(3))) uint32_t*)lds, 16, 0, 0);
}

// ---------------- K1: Khat[s][m] = Re( sum_n A^s * B_n * C[m,n] ) ----------------
__global__ void kgen(const float* __restrict__ A_re, const float* __restrict__ A_im,
                     const float* __restrict__ B_re, const float* __restrict__ B_im,
                     const float* __restrict__ C_re, const float* __restrict__ C_im,
                     float* __restrict__ Khat) {
  int s = blockIdx.x;
  int tid = threadIdx.x;
  __shared__ float Pr[64], Pi[64];
  if (tid < 64) {
    float ar = A_re[tid], ai = A_im[tid];
    float pr, pi;
    if (s == 0) { pr = 1.f; pi = 0.f; }
    else {
      float r2 = ar * ar + ai * ai;
      float rs = expf(0.5f * (float)s * logf(r2));
      float ang = (float)s * atan2f(ai, ar);
      pr = rs * cosf(ang); pi = rs * sinf(ang);
    }
    float br = B_re[tid], bi = B_im[tid];
    Pr[tid] = pr * br - pi * bi;
    Pi[tid] = pr * bi + pi * br;
  }
  __syncthreads();
  for (int m = tid; m < DM; m += 256) {
    const float* cr = C_re + (size_t)m * 64;
    const float* ci = C_im + (size_t)m * 64;
    float acc = 0.f;
    #pragma unroll
    for (int n = 0; n < 64; ++n) acc += Pr[n] * cr[n] - Pi[n] * ci[n];
    Khat[(size_t)s * DM + m] = acc;
  }
}

// ---------------- K0: fp32 -> bf16 streaming convert (8 elems/thread) ------------
__global__ __launch_bounds__(256) void cvt_bf16(const float* __restrict__ src,
                                                ushort* __restrict__ dst, int n8) {
  int i = blockIdx.x * 256 + threadIdx.x;
  if (i >= n8) return;
  const f32x4* s = (const f32x4*)src + (size_t)i * 2;
  f32x4 a = s[0], b = s[1];
  ushort8 o;
  #pragma unroll
  for (int e = 0; e < 4; ++e) { o[e] = f2bf(a[e]); o[4 + e] = f2bf(b[e]); }
  *(ushort8*)(dst + (size_t)i * 8) = o;
}

// ---------------- K2: bf16 MFMA GEMM (m97 structure) -----------------------------
// 128x128 tile, BK=64, 4 waves (2x2), global_load_lds width=16, linear LDS.
__global__ __launch_bounds__(256) void gemm_bias(const ushort* __restrict__ Xb,
                                                 const ushort* __restrict__ Wb,
                                                 const float* __restrict__ bias,
                                                 float* __restrict__ Y) {
  __shared__ ushort As[128 * 64];
  __shared__ ushort Bs[128 * 64];
  int wg = blockIdx.x;                       // 1024 blocks, 1024 % 8 == 0
  int swz = (wg & 7) * 128 + (wg >> 3);      // XCD-aware swizzle
  int bm = swz >> 3, bn = swz & 7;
  int tid = threadIdx.x;
  int lane = tid & 63, wid = tid >> 6;
  int wr = wid >> 1, wc = wid & 1;

  f32x4 acc[4][4];
  #pragma unroll
  for (int i = 0; i < 4; ++i)
    #pragma unroll
    for (int j = 0; j < 4; ++j) acc[i][j] = (f32x4){0.f, 0.f, 0.f, 0.f};

  // staging geometry: one gload16 call/wave = 1KB = 8 rows x 64 bf16
  int srow = lane >> 3;            // row within 8-row group
  int scol = (lane & 7) * 8;       // bf16 col offset
  const ushort* xb = Xb + ((size_t)bm * 128) * DM + scol;
  const ushort* wb = Wb + ((size_t)bn * 128) * DM + scol;

  for (int k0 = 0; k0 < DM; k0 += 64) {
    #pragma unroll
    for (int j = 0; j < 4; ++j) {
      int rbase = wid * 32 + j * 8;
      gload16(xb + (size_t)(rbase + srow) * DM + k0, As + rbase * 64);
      gload16(wb + (size_t)(rbase + srow) * DM + k0, Bs + rbase * 64);
    }
    __syncthreads();
    int fr = lane & 15, kg = lane >> 4;
    #pragma unroll
    for (int kk = 0; kk < 2; ++kk) {
      short8 af[4], bfr[4];
      #pragma unroll
      for (int mi = 0; mi < 4; ++mi)
        af[mi] = *(const short8*)(As + (wr * 64 + mi * 16 + fr) * 64 + kk * 32 + kg * 8);
      #pragma unroll
      for (int ni = 0; ni < 4; ++ni)
        bfr[ni] = *(const short8*)(Bs + (wc * 64 + ni * 16 + fr) * 64 + kk * 32 + kg * 8);
      #pragma unroll
      for (int mi = 0; mi < 4; ++mi)
        #pragma unroll
        for (int ni = 0; ni < 4; ++ni)
          acc[mi][ni] = __builtin_amdgcn_mfma_f32_16x16x32_bf16(af[mi], bfr[ni], acc[mi][ni], 0, 0, 0);
    }
    __syncthreads();
  }
  // epilogue: C/D layout col = lane&15, row = (lane>>4)*4 + j  [m89-verified]
  int fr = lane & 15, fq = lane >> 4;
  #pragma unroll
  for (int ni = 0; ni < 4; ++ni) {
    int col = bn * 128 + wc * 64 + ni * 16 + fr;
    float bvv = bias[col];
    #pragma unroll
    for (int mi = 0; mi < 4; ++mi) {
      int row = bm * 128 + wr * 64 + mi * 16 + fq * 4;
      #pragma unroll
      for (int j = 0; j < 4; ++j)
        Y[(size_t)(row + j) * DM + col] = acc[mi][ni][j] + bvv;
    }
  }
}

// ---------------- K3: LayerNorm in-place over last dim (1024) --------------------
__global__ __launch_bounds__(256) void ln_kernel(float* __restrict__ Y,
                                                 const float* __restrict__ gamma,
                                                 const float* __restrict__ beta) {
  size_t row = blockIdx.x;
  float* p = Y + row * DM;
  int tid = threadIdx.x;
  f32x4 v = *(f32x4*)(p + tid * 4);
  float s = v[0] + v[1] + v[2] + v[3];
  float s2 = v[0] * v[0] + v[1] * v[1] + v[2] * v[2] + v[3] * v[3];
  #pragma unroll
  for (int d = 32; d >= 1; d >>= 1) {
    s += __shfl_xor(s, d);
    s2 += __shfl_xor(s2, d);
  }
  __shared__ float red[8];
  int lane = tid & 63, wid = tid >> 6;
  if (lane == 0) { red[wid] = s; red[4 + wid] = s2; }
  __syncthreads();
  s = red[0] + red[1] + red[2] + red[3];
  s2 = red[4] + red[5] + red[6] + red[7];
  float mu = s * (1.f / DM);
  float var = s2 * (1.f / DM) - mu * mu;
  float inv = rsqrtf(var + 1e-5f);
  f32x4 g = *(const f32x4*)(gamma + tid * 4);
  f32x4 be = *(const f32x4*)(beta + tid * 4);
  f32x4 o;
  #pragma unroll
  for (int e = 0; e < 4; ++e) o[e] = (v[e] - mu) * inv * g[e] + be[e];
  *(f32x4*)(p + tid * 4) = o;
}

// ---------------- K4: out = xln + FIR(Khat) + D_re * cumsum(xln), IN-PLACE -------
// halo carried in LDS across chunks -> safe to read and write the same buffer.
__global__ __launch_bounds__(256) void ssm_kernel(const float* __restrict__ Xln,
                                                  const float* __restrict__ Khat,
                                                  const float* __restrict__ D_re,
                                                  float* __restrict__ Out) {
  __shared__ float xs[TC + TT][MT + 1];   // +1 pad
  __shared__ float cum[TC][MT + 1];
  __shared__ float kh[TT][MT];
  int blk = blockIdx.x;
  int b = blk >> 6;                  // 64 m-tiles per batch
  int m0 = (blk & 63) * MT;
  int tid = threadIdx.x;
  int lm = tid & 15, lr = tid >> 4;  // load/store roles (coalesced)
  int m_ = tid >> 4, tg = tid & 15;  // compute roles

  for (int j = tid; j < TT * MT; j += 256)
    kh[j >> 4][j & 15] = Khat[(size_t)(j >> 4) * DM + m0 + (j & 15)];
  float dre = D_re[m0 + m_];
  float carry = 0.f;

  for (int c = 0; c < L_SEQ / TC; ++c) {
    int cs = c * TC;
    // phase 0: halo — zeros for c==0, else carry last TT rows forward
    for (int j = tid; j < TT * MT; j += 256) {
      int r = j >> 4, m = j & 15;
      xs[r][m] = (c == 0) ? 0.f : xs[TC + r][m];
    }
    __syncthreads();
    // phase 1: load fresh TC rows (not yet overwritten by this block)
    #pragma unroll
    for (int j = 0; j < TC / 16; ++j) {
      int r = j * 16 + lr;
      xs[TT + r][lm] = Xln[((size_t)(b * L_SEQ + cs + r)) * DM + m0 + lm];
    }
    __syncthreads();
    // phase 2: cumsum (serial 16 + shuffle scan over 16 groups)
    float sl = 0.f;
    #pragma unroll
    for (int i = 0; i < 16; ++i) sl += xs[TT + tg * 16 + i][m_];
    float inc = sl;
    #pragma unroll
    for (int d = 1; d < 16; d <<= 1) {
      float o = __shfl_up(inc, d, 16);
      if (tg >= d) inc += o;
    }
    float run = carry + inc - sl;
    #pragma unroll
    for (int i = 0; i < 16; ++i) {
      run += xs[TT + tg * 16 + i][m_];
      cum[tg * 16 + i][m_] = run;
    }
    carry += __shfl(inc, 15, 16);
    __syncthreads();
    // phase 3: FIR + residual + D*cumsum
    float res[16];
    #pragma unroll
    for (int i = 0; i < 16; ++i) {
      int tl = tg + 16 * i;
      float acc = 0.f;
      #pragma unroll
      for (int s = 0; s < TT; ++s) acc += kh[s][m_] * xs[TT + tl - s][m_];
      res[i] = xs[TT + tl][m_] + acc + dre * cum[tl][m_];
    }
    __syncthreads();
    #pragma unroll
    for (int i = 0; i < 16; ++i) cum[tg + 16 * i][m_] = res[i];
    __syncthreads();
    // phase 4: coalesced store (in-place over rows this chunk already consumed)
    #pragma unroll
    for (int j = 0; j < TC / 16; ++j) {
      int r = j * 16 + lr;
      Out[((size_t)(b * L_SEQ + cs + r)) * DM + m0 + lm] = cum[r][lm];
    }
    __syncthreads();
  }
}

extern "C" void kernel_launch(void* const* d_in, const int* in_sizes, int n_in,
                              void* d_out, int out_size, void* d_ws, size_t ws_size,
                              hipStream_t stream) {
  const float* x     = (const float*)d_in[0];
  const float* W     = (const float*)d_in[1];
  const float* b_in  = (const float*)d_in[2];
  const float* gamma = (const float*)d_in[3];
  const float* beta  = (const float*)d_in[4];
  const float* A_re  = (const float*)d_in[5];
  const float* A_im  = (const float*)d_in[6];
  const float* B_re  = (const float*)d_in[7];
  const float* B_im  = (const float*)d_in[8];
  const float* C_re  = (const float*)d_in[9];
  const float* C_im  = (const float*)d_in[10];
  const float* D_re  = (const float*)d_in[11];
  // d_in[12] = D_im: dead — reference keeps only Re(conv)

  float* y    = (float*)d_out;                 // GEMM out -> LN in-place -> SSM in-place
  float* khat = (float*)d_ws;                  // 32*1024 fp32 = 128KB
  ushort* Xbf = (ushort*)((char*)d_ws + 131072);            // 16M bf16 = 32MB
  ushort* Wbf = Xbf + (size_t)16 * 1024 * 1024;             // 1M bf16 = 2MB

  const int NX = 8 * L_SEQ * DM;   // 16777216
  const int NW = DM * DM;          // 1048576

  kgen<<<TT, 256, 0, stream>>>(A_re, A_im, B_re, B_im, C_re, C_im, khat);
  cvt_bf16<<<NX / 8 / 256, 256, 0, stream>>>(x, Xbf, NX / 8);
  cvt_bf16<<<NW / 8 / 256, 256, 0, stream>>>(W, Wbf, NW / 8);
  gemm_bias<<<1024, 256, 0, stream>>>(Xbf, Wbf, b_in, y);
  ln_kernel<<<8 * L_SEQ, 256, 0, stream>>>(y, gamma, beta);
  ssm_kernel<<<512, 256, 0, stream>>>(y, khat, D_re, y);
}

// Round 3
// 143.944 us; speedup vs baseline: 1.3385x; 1.3385x over previous
//
#include <hip/hip_runtime.h>
#include <stdint.h>

// S4Block: out = xln + FIR(Khat, xln) + D_re * cumsum(xln), xln = LN(x @ W^T + b)
// Pipeline: cvt(x->Xbf@d_out) ; gemm(Xbf,Wbf)->ybf16@ws + per-row (sum,sumsq) partials ;
//           finalize->mu,rs ; chunksum(ybf)->partial ; scan->excl ; ssm2(ybf)->d_out.
// LN applied on-the-fly at every ybf consumer. No LDS in SSM path (reg window FIR + in-lane cumsum).

typedef __attribute__((ext_vector_type(8))) short short8;           // 8 bf16 MFMA frag
typedef __attribute__((ext_vector_type(8))) unsigned short ushort8;
typedef __attribute__((ext_vector_type(4))) float f32x4;
typedef unsigned short ushort;

#define L_SEQ 2048
#define DM    1024
#define TT    32     // FIR taps (|A|^32 ~ 1e-14)
#define NC    16     // cumsum chunks
#define CL    128    // chunk length (NC*CL = L_SEQ)

__device__ __forceinline__ ushort f2bf(float f) {
  uint32_t u = __builtin_bit_cast(uint32_t, f);
  u += 0x7FFFu + ((u >> 16) & 1u);   // RNE
  return (ushort)(u >> 16);
}
__device__ __forceinline__ float bf2f(ushort u) {
  uint32_t w = ((uint32_t)u) << 16;
  return __builtin_bit_cast(float, w);
}
__device__ __forceinline__ void gload16(const void* g, void* lds) {
  __builtin_amdgcn_global_load_lds(
      (const __attribute__((address_space(1))) uint32_t*)g,
      (__attribute__((address_space(3))) uint32_t*)lds, 16, 0, 0);
}

// ---------------- K1: Khat[s][m] = Re( sum_n A^s * B_n * C[m,n] ) ----------------
__global__ void kgen(const float* __restrict__ A_re, const float* __restrict__ A_im,
                     const float* __restrict__ B_re, const float* __restrict__ B_im,
                     const float* __restrict__ C_re, const float* __restrict__ C_im,
                     float* __restrict__ Khat) {
  int s = blockIdx.x;
  int tid = threadIdx.x;
  __shared__ float Pr[64], Pi[64];
  if (tid < 64) {
    float ar = A_re[tid], ai = A_im[tid];
    float pr, pi;
    if (s == 0) { pr = 1.f; pi = 0.f; }
    else {
      float r2 = ar * ar + ai * ai;
      float rsf = expf(0.5f * (float)s * logf(r2));
      float ang = (float)s * atan2f(ai, ar);
      pr = rsf * cosf(ang); pi = rsf * sinf(ang);
    }
    float br = B_re[tid], bi = B_im[tid];
    Pr[tid] = pr * br - pi * bi;
    Pi[tid] = pr * bi + pi * br;
  }
  __syncthreads();
  for (int m = tid; m < DM; m += 256) {
    const float* cr = C_re + (size_t)m * 64;
    const float* ci = C_im + (size_t)m * 64;
    float acc = 0.f;
    #pragma unroll
    for (int n = 0; n < 64; ++n) acc += Pr[n] * cr[n] - Pi[n] * ci[n];
    Khat[(size_t)s * DM + m] = acc;
  }
}

// ---------------- K0: fp32 -> bf16 streaming convert (8 elems/thread) ------------
__global__ __launch_bounds__(256) void cvt_bf16(const float* __restrict__ src,
                                                ushort* __restrict__ dst, int n8) {
  int i = blockIdx.x * 256 + threadIdx.x;
  if (i >= n8) return;
  const f32x4* s = (const f32x4*)src + (size_t)i * 2;
  f32x4 a = s[0], b = s[1];
  ushort8 o;
  #pragma unroll
  for (int e = 0; e < 4; ++e) { o[e] = f2bf(a[e]); o[4 + e] = f2bf(b[e]); }
  *(ushort8*)(dst + (size_t)i * 8) = o;
}

// ---------------- K2: bf16 MFMA GEMM + bias + bf16 store + row (sum,sumsq) -------
__global__ __launch_bounds__(256) void gemm_bias(const ushort* __restrict__ Xb,
                                                 const ushort* __restrict__ Wb,
                                                 const float* __restrict__ bias,
                                                 ushort* __restrict__ Yb,
                                                 float2* __restrict__ rowpart) {
  __shared__ ushort As[128 * 64];
  __shared__ ushort Bs[128 * 64];
  int wg = blockIdx.x;
  int swz = (wg & 7) * 128 + (wg >> 3);      // XCD-aware swizzle (1024 % 8 == 0)
  int bm = swz >> 3, bn = swz & 7;
  int tid = threadIdx.x;
  int lane = tid & 63, wid = tid >> 6;
  int wr = wid >> 1, wc = wid & 1;

  f32x4 acc[4][4];
  #pragma unroll
  for (int i = 0; i < 4; ++i)
    #pragma unroll
    for (int j = 0; j < 4; ++j) acc[i][j] = (f32x4){0.f, 0.f, 0.f, 0.f};

  int srow = lane >> 3;
  int scol = (lane & 7) * 8;
  const ushort* xb = Xb + ((size_t)bm * 128) * DM + scol;
  const ushort* wb = Wb + ((size_t)bn * 128) * DM + scol;

  for (int k0 = 0; k0 < DM; k0 += 64) {
    #pragma unroll
    for (int j = 0; j < 4; ++j) {
      int rbase = wid * 32 + j * 8;
      gload16(xb + (size_t)(rbase + srow) * DM + k0, As + rbase * 64);
      gload16(wb + (size_t)(rbase + srow) * DM + k0, Bs + rbase * 64);
    }
    __syncthreads();
    int fr = lane & 15, kg = lane >> 4;
    #pragma unroll
    for (int kk = 0; kk < 2; ++kk) {
      short8 af[4], bfr[4];
      #pragma unroll
      for (int mi = 0; mi < 4; ++mi)
        af[mi] = *(const short8*)(As + (wr * 64 + mi * 16 + fr) * 64 + kk * 32 + kg * 8);
      #pragma unroll
      for (int ni = 0; ni < 4; ++ni)
        bfr[ni] = *(const short8*)(Bs + (wc * 64 + ni * 16 + fr) * 64 + kk * 32 + kg * 8);
      #pragma unroll
      for (int mi = 0; mi < 4; ++mi)
        #pragma unroll
        for (int ni = 0; ni < 4; ++ni)
          acc[mi][ni] = __builtin_amdgcn_mfma_f32_16x16x32_bf16(af[mi], bfr[ni], acc[mi][ni], 0, 0, 0);
    }
    __syncthreads();
  }
  // epilogue: C/D layout col = lane&15, row = (lane>>4)*4 + j
  int fr = lane & 15, fq = lane >> 4;
  float rsum[4][4], rsq[4][4];
  #pragma unroll
  for (int mi = 0; mi < 4; ++mi)
    #pragma unroll
    for (int j = 0; j < 4; ++j) { rsum[mi][j] = 0.f; rsq[mi][j] = 0.f; }
  #pragma unroll
  for (int ni = 0; ni < 4; ++ni) {
    int col = bn * 128 + wc * 64 + ni * 16 + fr;
    float bvv = bias[col];
    #pragma unroll
    for (int mi = 0; mi < 4; ++mi) {
      int row = bm * 128 + wr * 64 + mi * 16 + fq * 4;
      #pragma unroll
      for (int j = 0; j < 4; ++j) {
        float v = acc[mi][ni][j] + bvv;
        Yb[(size_t)(row + j) * DM + col] = f2bf(v);
        rsum[mi][j] += v; rsq[mi][j] += v * v;
      }
    }
  }
  // allreduce across the 16 fr-lanes of each fq group
  #pragma unroll
  for (int d = 1; d < 16; d <<= 1) {
    #pragma unroll
    for (int mi = 0; mi < 4; ++mi)
      #pragma unroll
      for (int j = 0; j < 4; ++j) {
        rsum[mi][j] += __shfl_xor(rsum[mi][j], d);
        rsq[mi][j]  += __shfl_xor(rsq[mi][j], d);
      }
  }
  float* ls = (float*)As;   // reuse LDS: [0,256) sums by [wc][r], [256,512) sumsq
  if (fr == 0) {
    #pragma unroll
    for (int mi = 0; mi < 4; ++mi)
      #pragma unroll
      for (int j = 0; j < 4; ++j) {
        int r = wr * 64 + mi * 16 + fq * 4 + j;
        ls[wc * 128 + r] = rsum[mi][j];
        ls[256 + wc * 128 + r] = rsq[mi][j];
      }
  }
  __syncthreads();
  if (tid < 128) {
    float s = ls[tid] + ls[128 + tid];
    float q = ls[256 + tid] + ls[384 + tid];
    rowpart[((size_t)(bm * 128 + tid)) * 8 + bn] = make_float2(s, q);
  }
}

// ---------------- K5: finalize per-row LN stats ----------------------------------
__global__ __launch_bounds__(256) void finalize_stats(const float2* __restrict__ rowpart,
                                                      float* __restrict__ mu,
                                                      float* __restrict__ rs) {
  int r = blockIdx.x * 256 + threadIdx.x;   // 16384 rows
  float s = 0.f, q = 0.f;
  #pragma unroll
  for (int n = 0; n < 8; ++n) { float2 p = rowpart[(size_t)r * 8 + n]; s += p.x; q += p.y; }
  float m_ = s * (1.f / DM);
  float v = q * (1.f / DM) - m_ * m_;
  mu[r] = m_;
  rs[r] = rsqrtf(v + 1e-5f);
}

// ---------------- K6: per-chunk sums of xln --------------------------------------
__global__ __launch_bounds__(256) void chunksum(const ushort* __restrict__ ybf,
                                                const float* __restrict__ mu,
                                                const float* __restrict__ rs,
                                                const float* __restrict__ gamma,
                                                const float* __restrict__ beta,
                                                float* __restrict__ partial) {
  int blk = blockIdx.x;                      // 8b x 16c x 4mg = 512
  int b = blk >> 6, c = (blk >> 2) & 15, mg = blk & 3;
  int m = mg * 256 + threadIdx.x;
  float g = gamma[m], be = beta[m];
  int bb = b * L_SEQ, cs = c * CL;
  float s = 0.f;
  #pragma unroll 8
  for (int t = cs; t < cs + CL; ++t) {
    float v = bf2f(ybf[(size_t)(bb + t) * DM + m]);
    s += (v - mu[bb + t]) * rs[bb + t] * g + be;
  }
  partial[((size_t)(b * NC + c)) * DM + m] = s;
}

// ---------------- K7: exclusive scan over chunks per (b,m) -----------------------
__global__ __launch_bounds__(256) void scan16(const float* __restrict__ partial,
                                              float* __restrict__ excl) {
  int i = blockIdx.x * 256 + threadIdx.x;    // 8192 = (b, m)
  int b = i >> 10, m = i & 1023;
  float r = 0.f;
  #pragma unroll
  for (int c = 0; c < NC; ++c) {
    size_t idx = ((size_t)(b * NC + c)) * DM + m;
    excl[idx] = r;
    r += partial[idx];
  }
}

// ---------------- K8: fused LN + FIR + cumsum + residual, lane-owns-channel ------
__global__ __launch_bounds__(256) void ssm2(const ushort* __restrict__ ybf,
                                            const float* __restrict__ mu,
                                            const float* __restrict__ rs,
                                            const float* __restrict__ gamma,
                                            const float* __restrict__ beta,
                                            const float* __restrict__ Khat,
                                            const float* __restrict__ D_re,
                                            const float* __restrict__ excl,
                                            float* __restrict__ Out) {
  int blk = blockIdx.x;                      // 8b x 16c x 4mg = 512
  int b = blk >> 6, c = (blk >> 2) & 15, mg = blk & 3;
  int m = mg * 256 + threadIdx.x;
  int bb = b * L_SEQ, cs = c * CL;

  float kh[TT];
  #pragma unroll
  for (int s = 0; s < TT; ++s) kh[s] = Khat[(size_t)s * DM + m];
  float g = gamma[m], be = beta[m], dre = D_re[m];
  float run = excl[((size_t)(b * NC + c)) * DM + m];

  float P[32], A[32];
  // halo: xln rows [cs-32, cs); zeros for c==0
  if (c == 0) {
    #pragma unroll
    for (int i = 0; i < 32; ++i) P[i] = 0.f;
  } else {
    #pragma unroll
    for (int i = 0; i < 32; ++i) {
      int t = cs - 32 + i;
      float v = bf2f(ybf[(size_t)(bb + t) * DM + m]);
      P[i] = (v - mu[bb + t]) * rs[bb + t] * g + be;
    }
  }
  #pragma unroll
  for (int i = 0; i < 32; ++i) {
    int t = cs + i;
    float v = bf2f(ybf[(size_t)(bb + t) * DM + m]);
    A[i] = (v - mu[bb + t]) * rs[bb + t] * g + be;
  }

  #pragma unroll 1
  for (int j = 0; j < CL / 32; ++j) {
    float B[32];
    if (j < CL / 32 - 1) {
      int tb = cs + (j + 1) * 32;
      #pragma unroll
      for (int i = 0; i < 32; ++i) {
        int t = tb + i;
        float v = bf2f(ybf[(size_t)(bb + t) * DM + m]);
        B[i] = (v - mu[bb + t]) * rs[bb + t] * g + be;
      }
    }
    #pragma unroll
    for (int i = 0; i < 32; ++i) {
      float fir = 0.f;
      #pragma unroll
      for (int s = 0; s < TT; ++s) {
        float xv = (i - s >= 0) ? A[i - s] : P[32 + i - s];
        fir += kh[s] * xv;
      }
      run += A[i];
      Out[(size_t)(bb + cs + j * 32 + i) * DM + m] = A[i] + fir + dre * run;
    }
    #pragma unroll
    for (int i = 0; i < 32; ++i) { P[i] = A[i]; A[i] = B[i]; }
  }
}

extern "C" void kernel_launch(void* const* d_in, const int* in_sizes, int n_in,
                              void* d_out, int out_size, void* d_ws, size_t ws_size,
                              hipStream_t stream) {
  const float* x     = (const float*)d_in[0];
  const float* W     = (const float*)d_in[1];
  const float* b_in  = (const float*)d_in[2];
  const float* gamma = (const float*)d_in[3];
  const float* beta  = (const float*)d_in[4];
  const float* A_re  = (const float*)d_in[5];
  const float* A_im  = (const float*)d_in[6];
  const float* B_re  = (const float*)d_in[7];
  const float* B_im  = (const float*)d_in[8];
  const float* C_re  = (const float*)d_in[9];
  const float* C_im  = (const float*)d_in[10];
  const float* D_re  = (const float*)d_in[11];
  // d_in[12] = D_im: dead — reference keeps only Re(conv)

  char* ws = (char*)d_ws;
  float*  khat    = (float*)(ws + 0);                    // 128KB
  ushort* Wbf     = (ushort*)(ws + (131072));            // 2MB
  ushort* ybf     = (ushort*)(ws + (131072 + 2097152));  // 32MB
  float2* rowpart = (float2*)(ws + 35782656);            // 1MB
  float*  mu      = (float*)(ws + 36831232);             // 64KB
  float*  rs      = (float*)(ws + 36896768);             // 64KB
  float*  partial = (float*)(ws + 36962304);             // 512KB
  float*  excl    = (float*)(ws + 37486592);             // 512KB

  ushort* Xbf = (ushort*)d_out;        // d_out as scratch; dead after gemm
  float*  out = (float*)d_out;

  const int NX = 8 * L_SEQ * DM;
  const int NW = DM * DM;

  kgen<<<TT, 256, 0, stream>>>(A_re, A_im, B_re, B_im, C_re, C_im, khat);
  cvt_bf16<<<NX / 8 / 256, 256, 0, stream>>>(x, Xbf, NX / 8);
  cvt_bf16<<<NW / 8 / 256, 256, 0, stream>>>(W, Wbf, NW / 8);
  gemm_bias<<<1024, 256, 0, stream>>>(Xbf, Wbf, b_in, ybf, rowpart);
  finalize_stats<<<64, 256, 0, stream>>>(rowpart, mu, rs);
  chunksum<<<512, 256, 0, stream>>>(ybf, mu, rs, gamma, beta, partial);
  scan16<<<32, 256, 0, stream>>>(partial, excl);
  ssm2<<<512, 256, 0, stream>>>(ybf, mu, rs, gamma, beta, khat, D_re, excl, out);
}

// Round 4
// 122.485 us; speedup vs baseline: 1.5730x; 1.1752x over previous
//
#include <hip/hip_runtime.h>
#include <stdint.h>

// S4Block: out = xln + FIR(Khat, xln) + D_re * cumsum(xln), xln = LN(x @ W^T + b)
// Pipeline: cvt(x->Xbf@d_out) ; gemm8ph(Xbf,Wbf)->ybf16@ws + per-row (sum,sumsq) ;
//           finalize->mu,rs ; chunksum ; scan ; ssm2 -> d_out.

typedef __attribute__((ext_vector_type(8))) short short8;           // 8 bf16 MFMA frag
typedef __attribute__((ext_vector_type(8))) unsigned short ushort8;
typedef __attribute__((ext_vector_type(4))) float f32x4;
typedef unsigned short ushort;

#define L_SEQ 2048
#define DM    1024
#define TT    32     // FIR taps (|A|^32 ~ 1e-14)
#define NC    16     // cumsum chunks
#define CL    128    // chunk length

__device__ __forceinline__ ushort f2bf(float f) {
  uint32_t u = __builtin_bit_cast(uint32_t, f);
  u += 0x7FFFu + ((u >> 16) & 1u);   // RNE
  return (ushort)(u >> 16);
}
__device__ __forceinline__ float bf2f(ushort u) {
  uint32_t w = ((uint32_t)u) << 16;
  return __builtin_bit_cast(float, w);
}
__device__ __forceinline__ void gload16(const void* g, void* lds_p) {
  __builtin_amdgcn_global_load_lds(
      (const __attribute__((address_space(1))) uint32_t*)g,
      (__attribute__((address_space(3))) uint32_t*)lds_p, 16, 0, 0);
}

// ---------------- K1: Khat[s][m] = Re( sum_n A^s * B_n * C[m,n] ) ----------------
__global__ void kgen(const float* __restrict__ A_re, const float* __restrict__ A_im,
                     const float* __restrict__ B_re, const float* __restrict__ B_im,
                     const float* __restrict__ C_re, const float* __restrict__ C_im,
                     float* __restrict__ Khat) {
  int s = blockIdx.x;
  int tid = threadIdx.x;
  __shared__ float Pr[64], Pi[64];
  if (tid < 64) {
    float ar = A_re[tid], ai = A_im[tid];
    float pr, pi;
    if (s == 0) { pr = 1.f; pi = 0.f; }
    else {
      float r2 = ar * ar + ai * ai;
      float rsf = expf(0.5f * (float)s * logf(r2));
      float ang = (float)s * atan2f(ai, ar);
      pr = rsf * cosf(ang); pi = rsf * sinf(ang);
    }
    float br = B_re[tid], bi = B_im[tid];
    Pr[tid] = pr * br - pi * bi;
    Pi[tid] = pr * bi + pi * br;
  }
  __syncthreads();
  for (int m = tid; m < DM; m += 256) {
    const float* cr = C_re + (size_t)m * 64;
    const float* ci = C_im + (size_t)m * 64;
    float acc = 0.f;
    #pragma unroll
    for (int n = 0; n < 64; ++n) acc += Pr[n] * cr[n] - Pi[n] * ci[n];
    Khat[(size_t)s * DM + m] = acc;
  }
}

// ---------------- K0: fp32 -> bf16 streaming convert -----------------------------
__global__ __launch_bounds__(256) void cvt_bf16(const float* __restrict__ src,
                                                ushort* __restrict__ dst, int n8) {
  int i = blockIdx.x * 256 + threadIdx.x;
  if (i >= n8) return;
  const f32x4* s = (const f32x4*)src + (size_t)i * 2;
  f32x4 a = s[0], b = s[1];
  ushort8 o;
  #pragma unroll
  for (int e = 0; e < 4; ++e) { o[e] = f2bf(a[e]); o[4 + e] = f2bf(b[e]); }
  *(ushort8*)(dst + (size_t)i * 8) = o;
}

// ---------------- K2: 256x256 8-phase bf16 MFMA GEMM (T2+T3+T4+T5) ---------------
// 8 waves (2Mx4N), BK=64, 128KB dynamic LDS double-buffer, XOR(row&7) 16B-slot
// swizzle applied on the GLOBAL source (linear gload_lds dest) and on ds_read.
// vmcnt(4) at phases 4/8 only. acc[8][4] f32x4.
#define SBAR() do { asm volatile("" ::: "memory"); __builtin_amdgcn_s_barrier(); asm volatile("" ::: "memory"); } while (0)
#define LGKM0() asm volatile("s_waitcnt lgkmcnt(0)" ::: "memory")

#define RD_A(ABASE, MH)                                                            \
  { _Pragma("unroll") for (int mi_ = 0; mi_ < 4; ++mi_) {                          \
      int row_ = wr * 128 + (MH) * 64 + mi_ * 16 + fr;                             \
      const char* rp_ = (const char*)(ABASE) + row_ * 128;                         \
      _Pragma("unroll") for (int kk_ = 0; kk_ < 2; ++kk_) {                        \
        int slot_ = kk_ * 4 + kg;                                                  \
        areg[mi_][kk_] = *(const short8*)(rp_ + (((slot_ ^ (row_ & 7)) << 4)));    \
      } } }

#define RD_B(DST, BBASE, NH)                                                       \
  { _Pragma("unroll") for (int ni_ = 0; ni_ < 2; ++ni_) {                          \
      int row_ = wn * 64 + (NH) * 32 + ni_ * 16 + fr;                              \
      const char* rp_ = (const char*)(BBASE) + row_ * 128;                         \
      _Pragma("unroll") for (int kk_ = 0; kk_ < 2; ++kk_) {                        \
        int slot_ = kk_ * 4 + kg;                                                  \
        DST[ni_][kk_] = *(const short8*)(rp_ + (((slot_ ^ (row_ & 7)) << 4)));     \
      } } }

#define MF(MH, NH, BV)                                                             \
  { _Pragma("unroll") for (int mi_ = 0; mi_ < 4; ++mi_)                            \
      _Pragma("unroll") for (int ni_ = 0; ni_ < 2; ++ni_) {                        \
        acc[(MH)*4+mi_][(NH)*2+ni_] = __builtin_amdgcn_mfma_f32_16x16x32_bf16(     \
            areg[mi_][0], BV[ni_][0], acc[(MH)*4+mi_][(NH)*2+ni_], 0, 0, 0);       \
        acc[(MH)*4+mi_][(NH)*2+ni_] = __builtin_amdgcn_mfma_f32_16x16x32_bf16(     \
            areg[mi_][1], BV[ni_][1], acc[(MH)*4+mi_][(NH)*2+ni_], 0, 0, 0); } }

#define STAGE(LDSHALF, GROW, TTI)                                                  \
  { const ushort* g_ = (GROW) + (size_t)(wid * 16 + rl) * DM + (TTI) * 64 + sl * 8;\
    gload16(g_,          (LDSHALF) + wid * 1024);                                  \
    gload16(g_ + 8 * DM, (LDSHALF) + wid * 1024 + 512); }

__global__ __launch_bounds__(512, 2) void gemm_bias(const ushort* __restrict__ Xb,
                                                    const ushort* __restrict__ Wb,
                                                    const float* __restrict__ bias,
                                                    ushort* __restrict__ Yb,
                                                    float2* __restrict__ rowpart) {
  extern __shared__ ushort lds[];
  ushort* A0 = lds;                 // buf0 A tile [256][64] bf16 (32KB)
  ushort* B0 = lds + 16384;
  ushort* A1 = lds + 32768;
  ushort* B1 = lds + 49152;

  int wg = blockIdx.x;                        // 256 blocks = (64 bm) x (4 bn)
  int swz = (wg & 7) * 32 + (wg >> 3);        // XCD swizzle (256 % 8 == 0)
  int bm = swz >> 2, bn = swz & 3;
  int tid = threadIdx.x;
  int lane = tid & 63, wid = tid >> 6;        // 8 waves
  int wr = wid >> 2, wn = wid & 3;            // 2M x 4N
  int fr = lane & 15, kg = lane >> 4;         // frag-read roles
  int rl = lane >> 3, sl = (lane & 7) ^ rl;   // staging roles (pre-swizzled source)

  const ushort* XgT = Xb + (size_t)(bm * 256) * DM;   // A rows 0..127
  const ushort* XgB = XgT + (size_t)128 * DM;         // A rows 128..255
  const ushort* WgT = Wb + (size_t)(bn * 256) * DM;
  const ushort* WgX = WgT + (size_t)128 * DM;

  f32x4 acc[8][4];
  #pragma unroll
  for (int i = 0; i < 8; ++i)
    #pragma unroll
    for (int j = 0; j < 4; ++j) acc[i][j] = (f32x4){0.f, 0.f, 0.f, 0.f};
  short8 areg[4][2], bt[2][2], bb[2][2];

  // prologue: tile0 (all 4 halves) + tile1 B halves; vmcnt(4) -> tile0 landed
  STAGE(A0,         XgT, 0);
  STAGE(A0 + 8192,  XgB, 0);
  STAGE(B0,         WgT, 0);
  STAGE(B0 + 8192,  WgX, 0);
  STAGE(B1,         WgT, 1);
  STAGE(B1 + 8192,  WgX, 1);
  asm volatile("s_waitcnt vmcnt(4)" ::: "memory");
  SBAR();

  #pragma unroll 1
  for (int t = 0; t < 8; ++t) {
    int o = 2 * t + 1, n0 = 2 * t + 2, n1 = 2 * t + 3;
    bool stg = (t < 7);
    // ph1: read tile2t A-half(wave) mh=0 + B nh=0 ; stage A1-top <- tile o
    RD_A(A0, 0); RD_B(bt, B0, 0);
    STAGE(A1, XgT, o);
    SBAR(); LGKM0();
    __builtin_amdgcn_s_setprio(1); MF(0, 0, bt); __builtin_amdgcn_s_setprio(0);
    SBAR();
    // ph2
    RD_B(bb, B0, 1);
    STAGE(A1 + 8192, XgB, o);
    SBAR(); LGKM0();
    __builtin_amdgcn_s_setprio(1); MF(0, 1, bb); __builtin_amdgcn_s_setprio(0);
    SBAR();
    // ph3
    RD_A(A0, 1);
    if (stg) STAGE(B0, WgT, n0);
    SBAR(); LGKM0();
    __builtin_amdgcn_s_setprio(1); MF(1, 1, bb); __builtin_amdgcn_s_setprio(0);
    SBAR();
    // ph4  (vmcnt: retire A1<-tile o staged at ph1/ph2 before ph5 reads it)
    if (stg) {
      STAGE(B0 + 8192, WgX, n0);
      asm volatile("s_waitcnt vmcnt(4)" ::: "memory");
    } else {
      asm volatile("s_waitcnt vmcnt(0)" ::: "memory");
    }
    SBAR(); LGKM0();
    __builtin_amdgcn_s_setprio(1); MF(1, 0, bt); __builtin_amdgcn_s_setprio(0);
    SBAR();
    // ph5: tile 2t+1 from buf1
    RD_A(A1, 0); RD_B(bt, B1, 0);
    if (stg) STAGE(A0, XgT, n0);
    SBAR(); LGKM0();
    __builtin_amdgcn_s_setprio(1); MF(0, 0, bt); __builtin_amdgcn_s_setprio(0);
    SBAR();
    // ph6
    RD_B(bb, B1, 1);
    if (stg) STAGE(A0 + 8192, XgB, n0);
    SBAR(); LGKM0();
    __builtin_amdgcn_s_setprio(1); MF(0, 1, bb); __builtin_amdgcn_s_setprio(0);
    SBAR();
    // ph7
    RD_A(A1, 1);
    if (stg) STAGE(B1, WgT, n1);
    SBAR(); LGKM0();
    __builtin_amdgcn_s_setprio(1); MF(1, 1, bb); __builtin_amdgcn_s_setprio(0);
    SBAR();
    // ph8  (vmcnt: retire B0/A0 <- tile n0 before next ph1 reads them)
    if (stg) {
      STAGE(B1 + 8192, WgX, n1);
      asm volatile("s_waitcnt vmcnt(4)" ::: "memory");
    } else {
      asm volatile("s_waitcnt vmcnt(0)" ::: "memory");
    }
    SBAR(); LGKM0();
    __builtin_amdgcn_s_setprio(1); MF(1, 0, bt); __builtin_amdgcn_s_setprio(0);
    SBAR();
  }

  // ---------------- epilogue: bias + bf16 store + row (sum,sumsq) ----------------
  asm volatile("s_waitcnt vmcnt(0) lgkmcnt(0)" ::: "memory");
  __syncthreads();
  float* lsS = (float*)lds;          // [4 wn][256 rows]
  float* lsQ = lsS + 1024;
  int fq = lane >> 4;
  float bv[4];
  #pragma unroll
  for (int ni = 0; ni < 4; ++ni) bv[ni] = bias[bn * 256 + wn * 64 + ni * 16 + fr];
  #pragma unroll
  for (int mi = 0; mi < 8; ++mi) {
    float rs_[4] = {0.f, 0.f, 0.f, 0.f}, rq_[4] = {0.f, 0.f, 0.f, 0.f};
    #pragma unroll
    for (int ni = 0; ni < 4; ++ni) {
      int gcol = bn * 256 + wn * 64 + ni * 16 + fr;
      #pragma unroll
      for (int j = 0; j < 4; ++j) {
        float v = acc[mi][ni][j] + bv[ni];
        int grow = bm * 256 + wr * 128 + mi * 16 + fq * 4 + j;
        Yb[(size_t)grow * DM + gcol] = f2bf(v);
        rs_[j] += v; rq_[j] += v * v;
      }
    }
    #pragma unroll
    for (int d = 1; d < 16; d <<= 1)
      #pragma unroll
      for (int j = 0; j < 4; ++j) {
        rs_[j] += __shfl_xor(rs_[j], d);
        rq_[j] += __shfl_xor(rq_[j], d);
      }
    if (fr == 0) {
      #pragma unroll
      for (int j = 0; j < 4; ++j) {
        int r = wr * 128 + mi * 16 + fq * 4 + j;
        lsS[wn * 256 + r] = rs_[j];
        lsQ[wn * 256 + r] = rq_[j];
      }
    }
  }
  __syncthreads();
  if (tid < 256) {
    float s = lsS[tid] + lsS[256 + tid] + lsS[512 + tid] + lsS[768 + tid];
    float q = lsQ[tid] + lsQ[256 + tid] + lsQ[512 + tid] + lsQ[768 + tid];
    rowpart[((size_t)(bm * 256 + tid)) * 4 + bn] = make_float2(s, q);
  }
}

// ---------------- K5: finalize per-row LN stats ----------------------------------
__global__ __launch_bounds__(256) void finalize_stats(const float2* __restrict__ rowpart,
                                                      float* __restrict__ mu,
                                                      float* __restrict__ rs) {
  int r = blockIdx.x * 256 + threadIdx.x;   // 16384 rows
  float s = 0.f, q = 0.f;
  #pragma unroll
  for (int n = 0; n < 4; ++n) { float2 p = rowpart[(size_t)r * 4 + n]; s += p.x; q += p.y; }
  float m_ = s * (1.f / DM);
  float v = q * (1.f / DM) - m_ * m_;
  mu[r] = m_;
  rs[r] = rsqrtf(v + 1e-5f);
}

// ---------------- K6: per-chunk sums of xln --------------------------------------
__global__ __launch_bounds__(256) void chunksum(const ushort* __restrict__ ybf,
                                                const float* __restrict__ mu,
                                                const float* __restrict__ rs,
                                                const float* __restrict__ gamma,
                                                const float* __restrict__ beta,
                                                float* __restrict__ partial) {
  int blk = blockIdx.x;                      // 8b x 16c x 4mg = 512
  int b = blk >> 6, c = (blk >> 2) & 15, mg = blk & 3;
  int m = mg * 256 + threadIdx.x;
  float g = gamma[m], be = beta[m];
  int bb = b * L_SEQ, cs = c * CL;
  float s = 0.f;
  #pragma unroll 8
  for (int t = cs; t < cs + CL; ++t) {
    float v = bf2f(ybf[(size_t)(bb + t) * DM + m]);
    s += (v - mu[bb + t]) * rs[bb + t] * g + be;
  }
  partial[((size_t)(b * NC + c)) * DM + m] = s;
}

// ---------------- K7: exclusive scan over chunks per (b,m) -----------------------
__global__ __launch_bounds__(256) void scan16(const float* __restrict__ partial,
                                              float* __restrict__ excl) {
  int i = blockIdx.x * 256 + threadIdx.x;    // 8192 = (b, m)
  int b = i >> 10, m = i & 1023;
  float r = 0.f;
  #pragma unroll
  for (int c = 0; c < NC; ++c) {
    size_t idx = ((size_t)(b * NC + c)) * DM + m;
    excl[idx] = r;
    r += partial[idx];
  }
}

// ---------------- K8: fused LN + FIR + cumsum + residual, lane-owns-channel ------
__global__ __launch_bounds__(256) void ssm2(const ushort* __restrict__ ybf,
                                            const float* __restrict__ mu,
                                            const float* __restrict__ rs,
                                            const float* __restrict__ gamma,
                                            const float* __restrict__ beta,
                                            const float* __restrict__ Khat,
                                            const float* __restrict__ D_re,
                                            const float* __restrict__ excl,
                                            float* __restrict__ Out) {
  int blk = blockIdx.x;                      // 8b x 16c x 4mg = 512
  int b = blk >> 6, c = (blk >> 2) & 15, mg = blk & 3;
  int m = mg * 256 + threadIdx.x;
  int bb = b * L_SEQ, cs = c * CL;

  float kh[TT];
  #pragma unroll
  for (int s = 0; s < TT; ++s) kh[s] = Khat[(size_t)s * DM + m];
  float g = gamma[m], be = beta[m], dre = D_re[m];
  float run = excl[((size_t)(b * NC + c)) * DM + m];

  float P[32], A[32];
  if (c == 0) {
    #pragma unroll
    for (int i = 0; i < 32; ++i) P[i] = 0.f;
  } else {
    #pragma unroll
    for (int i = 0; i < 32; ++i) {
      int t = cs - 32 + i;
      float v = bf2f(ybf[(size_t)(bb + t) * DM + m]);
      P[i] = (v - mu[bb + t]) * rs[bb + t] * g + be;
    }
  }
  #pragma unroll
  for (int i = 0; i < 32; ++i) {
    int t = cs + i;
    float v = bf2f(ybf[(size_t)(bb + t) * DM + m]);
    A[i] = (v - mu[bb + t]) * rs[bb + t] * g + be;
  }

  #pragma unroll 1
  for (int j = 0; j < CL / 32; ++j) {
    float B[32];
    if (j < CL / 32 - 1) {
      int tb = cs + (j + 1) * 32;
      #pragma unroll
      for (int i = 0; i < 32; ++i) {
        int t = tb + i;
        float v = bf2f(ybf[(size_t)(bb + t) * DM + m]);
        B[i] = (v - mu[bb + t]) * rs[bb + t] * g + be;
      }
    }
    #pragma unroll
    for (int i = 0; i < 32; ++i) {
      float fir = 0.f;
      #pragma unroll
      for (int s = 0; s < TT; ++s) {
        float xv = (i - s >= 0) ? A[i - s] : P[32 + i - s];
        fir += kh[s] * xv;
      }
      run += A[i];
      Out[(size_t)(bb + cs + j * 32 + i) * DM + m] = A[i] + fir + dre * run;
    }
    #pragma unroll
    for (int i = 0; i < 32; ++i) { P[i] = A[i]; A[i] = B[i]; }
  }
}

extern "C" void kernel_launch(void* const* d_in, const int* in_sizes, int n_in,
                              void* d_out, int out_size, void* d_ws, size_t ws_size,
                              hipStream_t stream) {
  const float* x     = (const float*)d_in[0];
  const float* W     = (const float*)d_in[1];
  const float* b_in  = (const float*)d_in[2];
  const float* gamma = (const float*)d_in[3];
  const float* beta  = (const float*)d_in[4];
  const float* A_re  = (const float*)d_in[5];
  const float* A_im  = (const float*)d_in[6];
  const float* B_re  = (const float*)d_in[7];
  const float* B_im  = (const float*)d_in[8];
  const float* C_re  = (const float*)d_in[9];
  const float* C_im  = (const float*)d_in[10];
  const float* D_re  = (const float*)d_in[11];
  // d_in[12] = D_im: dead — reference keeps only Re(conv)

  char* ws = (char*)d_ws;
  float*  khat    = (float*)(ws + 0);                    // 128KB
  ushort* Wbf     = (ushort*)(ws + (131072));            // 2MB
  ushort* ybf     = (ushort*)(ws + (131072 + 2097152));  // 32MB
  float2* rowpart = (float2*)(ws + 35782656);            // 512KB used
  float*  mu      = (float*)(ws + 36831232);             // 64KB
  float*  rs      = (float*)(ws + 36896768);             // 64KB
  float*  partial = (float*)(ws + 36962304);             // 512KB
  float*  excl    = (float*)(ws + 37486592);             // 512KB

  ushort* Xbf = (ushort*)d_out;        // d_out as scratch; dead after gemm
  float*  out = (float*)d_out;

  const int NX = 8 * L_SEQ * DM;
  const int NW = DM * DM;

  (void)hipFuncSetAttribute((const void*)gemm_bias,
                            hipFuncAttributeMaxDynamicSharedMemorySize, 131072);

  kgen<<<TT, 256, 0, stream>>>(A_re, A_im, B_re, B_im, C_re, C_im, khat);
  cvt_bf16<<<NX / 8 / 256, 256, 0, stream>>>(x, Xbf, NX / 8);
  cvt_bf16<<<NW / 8 / 256, 256, 0, stream>>>(W, Wbf, NW / 8);
  gemm_bias<<<256, 512, 131072, stream>>>(Xbf, Wbf, b_in, ybf, rowpart);
  finalize_stats<<<64, 256, 0, stream>>>(rowpart, mu, rs);
  chunksum<<<512, 256, 0, stream>>>(ybf, mu, rs, gamma, beta, partial);
  scan16<<<32, 256, 0, stream>>>(partial, excl);
  ssm2<<<512, 256, 0, stream>>>(ybf, mu, rs, gamma, beta, khat, D_re, excl, out);
}

// Round 5
// 110.845 us; speedup vs baseline: 1.7381x; 1.1050x over previous
//
#include <hip/hip_runtime.h>
#include <stdint.h>

// S4Block: out = xln + FIR(Khat, xln) + D_re * cumsum(xln), xln = LN(x @ W^T + b)
// Pipeline (4 launches): cvt_and_kgen ; gemm8ph -> ybf16 + rowpart(sum,sumsq) ;
//                        chunksum -> partial ; ssm2 (inline stats + inline scan) -> out.
// ws: khat 128KB | Wbf 2MB | ybf 32MB | rowpart 512KB | partial 512KB.  Xbf lives in d_out.

typedef __attribute__((ext_vector_type(8))) short short8;           // 8 bf16 MFMA frag
typedef __attribute__((ext_vector_type(8))) unsigned short ushort8;
typedef __attribute__((ext_vector_type(4))) float f32x4;
typedef unsigned short ushort;

#define L_SEQ 2048
#define DM    1024
#define TT    8      // FIR taps kept (|K| ~ 1e-6; tail < 1e-9 — D*cumsum is the real term)
#define NC    16     // cumsum chunks
#define CL    128    // chunk length

__device__ __forceinline__ ushort f2bf(float f) {
  uint32_t u = __builtin_bit_cast(uint32_t, f);
  u += 0x7FFFu + ((u >> 16) & 1u);   // RNE
  return (ushort)(u >> 16);
}
__device__ __forceinline__ float bf2f(ushort u) {
  uint32_t w = ((uint32_t)u) << 16;
  return __builtin_bit_cast(float, w);
}
__device__ __forceinline__ void gload16(const void* g, void* lds_p) {
  __builtin_amdgcn_global_load_lds(
      (const __attribute__((address_space(1))) uint32_t*)g,
      (__attribute__((address_space(3))) uint32_t*)lds_p, 16, 0, 0);
}

// ---------------- K0+K1: fused fp32->bf16 converts (x, W) + Khat generation ------
__global__ __launch_bounds__(256) void cvt_and_kgen(
    const float* __restrict__ x, const float* __restrict__ W,
    ushort* __restrict__ Xbf, ushort* __restrict__ Wbf,
    const float* __restrict__ A_re, const float* __restrict__ A_im,
    const float* __restrict__ B_re, const float* __restrict__ B_im,
    const float* __restrict__ C_re, const float* __restrict__ C_im,
    float* __restrict__ Khat, int nx8, int nw8, int cvtBlocks) {
  int blk = blockIdx.x;
  int tid = threadIdx.x;
  if (blk < cvtBlocks) {
    int i = blk * 256 + tid;
    const float* src; ushort* dst; int idx;
    if (i < nx8) { src = x; dst = Xbf; idx = i; }
    else         { src = W; dst = Wbf; idx = i - nx8; if (idx >= nw8) return; }
    const f32x4* s = (const f32x4*)src + (size_t)idx * 2;
    f32x4 a = s[0], b = s[1];
    ushort8 o;
    #pragma unroll
    for (int e = 0; e < 4; ++e) { o[e] = f2bf(a[e]); o[4 + e] = f2bf(b[e]); }
    *(ushort8*)(dst + (size_t)idx * 8) = o;
    return;
  }
  // kgen: Khat[s][m] = Re( sum_n A^s * B_n * C[m,n] )
  int s = blk - cvtBlocks;
  __shared__ float Pr[64], Pi[64];
  if (tid < 64) {
    float ar = A_re[tid], ai = A_im[tid];
    float pr, pi;
    if (s == 0) { pr = 1.f; pi = 0.f; }
    else {
      float r2 = ar * ar + ai * ai;
      float rsf = expf(0.5f * (float)s * logf(r2));
      float ang = (float)s * atan2f(ai, ar);
      pr = rsf * cosf(ang); pi = rsf * sinf(ang);
    }
    float br = B_re[tid], bi = B_im[tid];
    Pr[tid] = pr * br - pi * bi;
    Pi[tid] = pr * bi + pi * br;
  }
  __syncthreads();
  for (int m = tid; m < DM; m += 256) {
    const float* cr = C_re + (size_t)m * 64;
    const float* ci = C_im + (size_t)m * 64;
    float acc = 0.f;
    #pragma unroll
    for (int n = 0; n < 64; ++n) acc += Pr[n] * cr[n] - Pi[n] * ci[n];
    Khat[(size_t)s * DM + m] = acc;
  }
}

// ---------------- K2: 256x256 8-phase bf16 MFMA GEMM (T2+T3+T4+T5) ---------------
// (byte-identical main loop to round 4 — verified schedule; do not touch)
#define SBAR() do { asm volatile("" ::: "memory"); __builtin_amdgcn_s_barrier(); asm volatile("" ::: "memory"); } while (0)
#define LGKM0() asm volatile("s_waitcnt lgkmcnt(0)" ::: "memory")

#define RD_A(ABASE, MH)                                                            \
  { _Pragma("unroll") for (int mi_ = 0; mi_ < 4; ++mi_) {                          \
      int row_ = wr * 128 + (MH) * 64 + mi_ * 16 + fr;                             \
      const char* rp_ = (const char*)(ABASE) + row_ * 128;                         \
      _Pragma("unroll") for (int kk_ = 0; kk_ < 2; ++kk_) {                        \
        int slot_ = kk_ * 4 + kg;                                                  \
        areg[mi_][kk_] = *(const short8*)(rp_ + (((slot_ ^ (row_ & 7)) << 4)));    \
      } } }

#define RD_B(DST, BBASE, NH)                                                       \
  { _Pragma("unroll") for (int ni_ = 0; ni_ < 2; ++ni_) {                          \
      int row_ = wn * 64 + (NH) * 32 + ni_ * 16 + fr;                              \
      const char* rp_ = (const char*)(BBASE) + row_ * 128;                         \
      _Pragma("unroll") for (int kk_ = 0; kk_ < 2; ++kk_) {                        \
        int slot_ = kk_ * 4 + kg;                                                  \
        DST[ni_][kk_] = *(const short8*)(rp_ + (((slot_ ^ (row_ & 7)) << 4)));     \
      } } }

#define MF(MH, NH, BV)                                                             \
  { _Pragma("unroll") for (int mi_ = 0; mi_ < 4; ++mi_)                            \
      _Pragma("unroll") for (int ni_ = 0; ni_ < 2; ++ni_) {                        \
        acc[(MH)*4+mi_][(NH)*2+ni_] = __builtin_amdgcn_mfma_f32_16x16x32_bf16(     \
            areg[mi_][0], BV[ni_][0], acc[(MH)*4+mi_][(NH)*2+ni_], 0, 0, 0);       \
        acc[(MH)*4+mi_][(NH)*2+ni_] = __builtin_amdgcn_mfma_f32_16x16x32_bf16(     \
            areg[mi_][1], BV[ni_][1], acc[(MH)*4+mi_][(NH)*2+ni_], 0, 0, 0); } }

#define STAGE(LDSHALF, GROW, TTI)                                                  \
  { const ushort* g_ = (GROW) + (size_t)(wid * 16 + rl) * DM + (TTI) * 64 + sl * 8;\
    gload16(g_,          (LDSHALF) + wid * 1024);                                  \
    gload16(g_ + 8 * DM, (LDSHALF) + wid * 1024 + 512); }

__global__ __launch_bounds__(512, 2) void gemm_bias(const ushort* __restrict__ Xb,
                                                    const ushort* __restrict__ Wb,
                                                    const float* __restrict__ bias,
                                                    ushort* __restrict__ Yb,
                                                    float2* __restrict__ rowpart) {
  extern __shared__ ushort lds[];
  ushort* A0 = lds;
  ushort* B0 = lds + 16384;
  ushort* A1 = lds + 32768;
  ushort* B1 = lds + 49152;

  int wg = blockIdx.x;                        // 256 blocks = (64 bm) x (4 bn)
  int swz = (wg & 7) * 32 + (wg >> 3);        // XCD swizzle (256 % 8 == 0)
  int bm = swz >> 2, bn = swz & 3;
  int tid = threadIdx.x;
  int lane = tid & 63, wid = tid >> 6;        // 8 waves
  int wr = wid >> 2, wn = wid & 3;            // 2M x 4N
  int fr = lane & 15, kg = lane >> 4;
  int rl = lane >> 3, sl = (lane & 7) ^ rl;   // pre-swizzled global source

  const ushort* XgT = Xb + (size_t)(bm * 256) * DM;
  const ushort* XgB = XgT + (size_t)128 * DM;
  const ushort* WgT = Wb + (size_t)(bn * 256) * DM;
  const ushort* WgX = WgT + (size_t)128 * DM;

  f32x4 acc[8][4];
  #pragma unroll
  for (int i = 0; i < 8; ++i)
    #pragma unroll
    for (int j = 0; j < 4; ++j) acc[i][j] = (f32x4){0.f, 0.f, 0.f, 0.f};
  short8 areg[4][2], bt[2][2], bb[2][2];

  STAGE(A0,         XgT, 0);
  STAGE(A0 + 8192,  XgB, 0);
  STAGE(B0,         WgT, 0);
  STAGE(B0 + 8192,  WgX, 0);
  STAGE(B1,         WgT, 1);
  STAGE(B1 + 8192,  WgX, 1);
  asm volatile("s_waitcnt vmcnt(4)" ::: "memory");
  SBAR();

  #pragma unroll 1
  for (int t = 0; t < 8; ++t) {
    int o = 2 * t + 1, n0 = 2 * t + 2, n1 = 2 * t + 3;
    bool stg = (t < 7);
    RD_A(A0, 0); RD_B(bt, B0, 0);
    STAGE(A1, XgT, o);
    SBAR(); LGKM0();
    __builtin_amdgcn_s_setprio(1); MF(0, 0, bt); __builtin_amdgcn_s_setprio(0);
    SBAR();
    RD_B(bb, B0, 1);
    STAGE(A1 + 8192, XgB, o);
    SBAR(); LGKM0();
    __builtin_amdgcn_s_setprio(1); MF(0, 1, bb); __builtin_amdgcn_s_setprio(0);
    SBAR();
    RD_A(A0, 1);
    if (stg) STAGE(B0, WgT, n0);
    SBAR(); LGKM0();
    __builtin_amdgcn_s_setprio(1); MF(1, 1, bb); __builtin_amdgcn_s_setprio(0);
    SBAR();
    if (stg) {
      STAGE(B0 + 8192, WgX, n0);
      asm volatile("s_waitcnt vmcnt(4)" ::: "memory");
    } else {
      asm volatile("s_waitcnt vmcnt(0)" ::: "memory");
    }
    SBAR(); LGKM0();
    __builtin_amdgcn_s_setprio(1); MF(1, 0, bt); __builtin_amdgcn_s_setprio(0);
    SBAR();
    RD_A(A1, 0); RD_B(bt, B1, 0);
    if (stg) STAGE(A0, XgT, n0);
    SBAR(); LGKM0();
    __builtin_amdgcn_s_setprio(1); MF(0, 0, bt); __builtin_amdgcn_s_setprio(0);
    SBAR();
    RD_B(bb, B1, 1);
    if (stg) STAGE(A0 + 8192, XgB, n0);
    SBAR(); LGKM0();
    __builtin_amdgcn_s_setprio(1); MF(0, 1, bb); __builtin_amdgcn_s_setprio(0);
    SBAR();
    RD_A(A1, 1);
    if (stg) STAGE(B1, WgT, n1);
    SBAR(); LGKM0();
    __builtin_amdgcn_s_setprio(1); MF(1, 1, bb); __builtin_amdgcn_s_setprio(0);
    SBAR();
    if (stg) {
      STAGE(B1 + 8192, WgX, n1);
      asm volatile("s_waitcnt vmcnt(4)" ::: "memory");
    } else {
      asm volatile("s_waitcnt vmcnt(0)" ::: "memory");
    }
    SBAR(); LGKM0();
    __builtin_amdgcn_s_setprio(1); MF(1, 0, bt); __builtin_amdgcn_s_setprio(0);
    SBAR();
  }

  asm volatile("s_waitcnt vmcnt(0) lgkmcnt(0)" ::: "memory");
  __syncthreads();
  float* lsS = (float*)lds;
  float* lsQ = lsS + 1024;
  int fq = lane >> 4;
  float bv[4];
  #pragma unroll
  for (int ni = 0; ni < 4; ++ni) bv[ni] = bias[bn * 256 + wn * 64 + ni * 16 + fr];
  #pragma unroll
  for (int mi = 0; mi < 8; ++mi) {
    float rs_[4] = {0.f, 0.f, 0.f, 0.f}, rq_[4] = {0.f, 0.f, 0.f, 0.f};
    #pragma unroll
    for (int ni = 0; ni < 4; ++ni) {
      int gcol = bn * 256 + wn * 64 + ni * 16 + fr;
      #pragma unroll
      for (int j = 0; j < 4; ++j) {
        float v = acc[mi][ni][j] + bv[ni];
        int grow = bm * 256 + wr * 128 + mi * 16 + fq * 4 + j;
        Yb[(size_t)grow * DM + gcol] = f2bf(v);
        rs_[j] += v; rq_[j] += v * v;
      }
    }
    #pragma unroll
    for (int d = 1; d < 16; d <<= 1)
      #pragma unroll
      for (int j = 0; j < 4; ++j) {
        rs_[j] += __shfl_xor(rs_[j], d);
        rq_[j] += __shfl_xor(rq_[j], d);
      }
    if (fr == 0) {
      #pragma unroll
      for (int j = 0; j < 4; ++j) {
        int r = wr * 128 + mi * 16 + fq * 4 + j;
        lsS[wn * 256 + r] = rs_[j];
        lsQ[wn * 256 + r] = rq_[j];
      }
    }
  }
  __syncthreads();
  if (tid < 256) {
    float s = lsS[tid] + lsS[256 + tid] + lsS[512 + tid] + lsS[768 + tid];
    float q = lsQ[tid] + lsQ[256 + tid] + lsQ[512 + tid] + lsQ[768 + tid];
    rowpart[((size_t)(bm * 256 + tid)) * 4 + bn] = make_float2(s, q);
  }
}

// ---------------- helper: per-row LN stats from rowpart --------------------------
__device__ __forceinline__ void row_stats(const float2* __restrict__ rowpart,
                                          int grow, float& mu_, float& rs_) {
  float s = 0.f, q = 0.f;
  #pragma unroll
  for (int n = 0; n < 4; ++n) { float2 p = rowpart[(size_t)grow * 4 + n]; s += p.x; q += p.y; }
  mu_ = s * (1.f / DM);
  float v = q * (1.f / DM) - mu_ * mu_;
  rs_ = rsqrtf(v + 1e-5f);
}

// ---------------- K6: per-chunk sums of xln (2 channels/thread, inline stats) ----
__global__ __launch_bounds__(256) void chunksum(const ushort* __restrict__ ybf,
                                                const float2* __restrict__ rowpart,
                                                const float* __restrict__ gamma,
                                                const float* __restrict__ beta,
                                                float* __restrict__ partial) {
  int blk = blockIdx.x;                      // 8b x 16c x 2mg = 256
  int b = blk >> 5, c = (blk >> 1) & 15, mg = blk & 1;
  int tid = threadIdx.x;
  int m2 = mg * 512 + tid * 2;
  int bb = b * L_SEQ, cs = c * CL;
  __shared__ float muL[CL], rsL[CL];
  if (tid < CL) row_stats(rowpart, bb + cs + tid, muL[tid], rsL[tid]);
  __syncthreads();
  float g0 = gamma[m2], g1 = gamma[m2 + 1], be0 = beta[m2], be1 = beta[m2 + 1];
  float s0 = 0.f, s1 = 0.f;
  const ushort* base = ybf + (size_t)(bb + cs) * DM + m2;
  #pragma unroll 8
  for (int t = 0; t < CL; ++t) {
    uint32_t v = *(const uint32_t*)(base + (size_t)t * DM);
    float f0 = bf2f((ushort)v), f1 = bf2f((ushort)(v >> 16));
    float r = rsL[t], mu_ = muL[t];
    s0 += (f0 - mu_) * r * g0 + be0;
    s1 += (f1 - mu_) * r * g1 + be1;
  }
  *(float2*)&partial[((size_t)(b * NC + c)) * DM + m2] = make_float2(s0, s1);
}

// ---------------- K8: fused LN + FIR(8) + cumsum + residual ----------------------
__global__ __launch_bounds__(256) void ssm2(const ushort* __restrict__ ybf,
                                            const float2* __restrict__ rowpart,
                                            const float* __restrict__ gamma,
                                            const float* __restrict__ beta,
                                            const float* __restrict__ Khat,
                                            const float* __restrict__ D_re,
                                            const float* __restrict__ partial,
                                            float* __restrict__ Out) {
  int blk = blockIdx.x;                      // 8b x 16c x 4mg = 512
  int b = blk >> 6, c = (blk >> 2) & 15, mg = blk & 3;
  int tid = threadIdx.x;
  int m = mg * 256 + tid;
  int bb = b * L_SEQ, cs = c * CL;

  __shared__ float muL[CL + TT], rsL[CL + TT];   // rows cs-TT .. cs+CL-1
  for (int r = tid; r < CL + TT; r += 256) {
    int row = cs - TT + r;
    if (row >= 0) row_stats(rowpart, bb + row, muL[r], rsL[r]);
    else { muL[r] = 0.f; rsL[r] = 0.f; }
  }
  __syncthreads();

  float kh[TT];
  #pragma unroll
  for (int s = 0; s < TT; ++s) kh[s] = Khat[(size_t)s * DM + m];
  float g = gamma[m], be = beta[m], dre = D_re[m];

  // inline exclusive scan over chunk partials
  float run = 0.f;
  for (int cc = 0; cc < c; ++cc) run += partial[((size_t)(b * NC + cc)) * DM + m];

  float P[TT], A[32];
  if (c == 0) {
    #pragma unroll
    for (int i = 0; i < TT; ++i) P[i] = 0.f;
  } else {
    #pragma unroll
    for (int i = 0; i < TT; ++i) {
      float v = bf2f(ybf[(size_t)(bb + cs - TT + i) * DM + m]);
      P[i] = (v - muL[i]) * rsL[i] * g + be;
    }
  }
  #pragma unroll
  for (int i = 0; i < 32; ++i) {
    float v = bf2f(ybf[(size_t)(bb + cs + i) * DM + m]);
    A[i] = (v - muL[TT + i]) * rsL[TT + i] * g + be;
  }

  #pragma unroll 1
  for (int j = 0; j < CL / 32; ++j) {
    float B[32];
    if (j < CL / 32 - 1) {
      int tb = (j + 1) * 32;
      #pragma unroll
      for (int i = 0; i < 32; ++i) {
        float v = bf2f(ybf[(size_t)(bb + cs + tb + i) * DM + m]);
        B[i] = (v - muL[TT + tb + i]) * rsL[TT + tb + i] * g + be;
      }
    }
    #pragma unroll
    for (int i = 0; i < 32; ++i) {
      float fir = 0.f;
      #pragma unroll
      for (int s = 0; s < TT; ++s) {
        float xv = (i - s >= 0) ? A[i - s] : P[TT + i - s];
        fir += kh[s] * xv;
      }
      run += A[i];
      Out[(size_t)(bb + cs + j * 32 + i) * DM + m] = A[i] + fir + dre * run;
    }
    #pragma unroll
    for (int i = 0; i < TT; ++i) P[i] = A[32 - TT + i];
    #pragma unroll
    for (int i = 0; i < 32; ++i) A[i] = B[i];
  }
}

extern "C" void kernel_launch(void* const* d_in, const int* in_sizes, int n_in,
                              void* d_out, int out_size, void* d_ws, size_t ws_size,
                              hipStream_t stream) {
  const float* x     = (const float*)d_in[0];
  const float* W     = (const float*)d_in[1];
  const float* b_in  = (const float*)d_in[2];
  const float* gamma = (const float*)d_in[3];
  const float* beta  = (const float*)d_in[4];
  const float* A_re  = (const float*)d_in[5];
  const float* A_im  = (const float*)d_in[6];
  const float* B_re  = (const float*)d_in[7];
  const float* B_im  = (const float*)d_in[8];
  const float* C_re  = (const float*)d_in[9];
  const float* C_im  = (const float*)d_in[10];
  const float* D_re  = (const float*)d_in[11];
  // d_in[12] = D_im: dead — reference keeps only Re(conv)

  char* ws = (char*)d_ws;
  float*  khat    = (float*)(ws + 0);                    // 128KB region
  ushort* Wbf     = (ushort*)(ws + 131072);              // 2MB
  ushort* ybf     = (ushort*)(ws + 2228224);             // 32MB
  float2* rowpart = (float2*)(ws + 35782656);            // 512KB
  float*  partial = (float*)(ws + 36306944);             // 512KB

  ushort* Xbf = (ushort*)d_out;        // d_out as scratch; dead after gemm
  float*  out = (float*)d_out;

  const int NX = 8 * L_SEQ * DM;       // 16777216
  const int NW = DM * DM;              // 1048576
  const int nx8 = NX / 8, nw8 = NW / 8;
  const int cvtBlocks = (nx8 + nw8) / 256;   // 8704 (exact)

  (void)hipFuncSetAttribute((const void*)gemm_bias,
                            hipFuncAttributeMaxDynamicSharedMemorySize, 131072);

  cvt_and_kgen<<<cvtBlocks + TT, 256, 0, stream>>>(x, W, Xbf, Wbf,
      A_re, A_im, B_re, B_im, C_re, C_im, khat, nx8, nw8, cvtBlocks);
  gemm_bias<<<256, 512, 131072, stream>>>(Xbf, Wbf, b_in, ybf, rowpart);
  chunksum<<<256, 256, 0, stream>>>(ybf, rowpart, gamma, beta, partial);
  ssm2<<<512, 256, 0, stream>>>(ybf, rowpart, gamma, beta, khat, D_re, partial, out);
}

// Round 6
// 100.591 us; speedup vs baseline: 1.9153x; 1.1019x over previous
//
#include <hip/hip_runtime.h>
#include <stdint.h>

// S4Block: out = xln + FIR(Khat, xln) + D_re * cumsum(xln), xln = LN(x @ W^T + b)
// Pipeline (4 launches): cvt_stream (x->Xbf@d_out, W->Wbf@ws) ; gemm8ph -> ybf16 +
//   rowpart(sum,sumsq) ; chunksum -> partial ; ssm2 (inline kgen + stats + scan) -> out.
// ws: Wbf 2MB | ybf 32MB | rowpart 512KB | partial 512KB  (~37MB < 64MB budget)

typedef __attribute__((ext_vector_type(8))) short short8;           // 8 bf16 MFMA frag
typedef __attribute__((ext_vector_type(8))) unsigned short ushort8;
typedef __attribute__((ext_vector_type(4))) float f32x4;
typedef unsigned short ushort;

#define L_SEQ 2048
#define DM    1024
#define TT    8      // FIR taps kept (|K| ~ 1e-6; D*cumsum is the real term)
#define NC    16     // cumsum chunks
#define CL    128    // chunk length

__device__ __forceinline__ ushort f2bf(float f) {
  uint32_t u = __builtin_bit_cast(uint32_t, f);
  u += 0x7FFFu + ((u >> 16) & 1u);   // RNE
  return (ushort)(u >> 16);
}
__device__ __forceinline__ float bf2f(ushort u) {
  uint32_t w = ((uint32_t)u) << 16;
  return __builtin_bit_cast(float, w);
}
__device__ __forceinline__ void gload16(const void* g, void* lds_p) {
  __builtin_amdgcn_global_load_lds(
      (const __attribute__((address_space(1))) uint32_t*)g,
      (__attribute__((address_space(3))) uint32_t*)lds_p, 16, 0, 0);
}

// ---------------- K0: fp32 -> bf16 grid-stride streamer (light VGPR) -------------
// blocks [0,2048): x (4 iters/thread) ; [2048,2176): W (4 iters/thread)
__global__ __launch_bounds__(256) void cvt_stream(const float* __restrict__ x,
                                                  ushort* __restrict__ Xbf,
                                                  const float* __restrict__ W,
                                                  ushort* __restrict__ Wbf) {
  int blk = blockIdx.x;
  const float* src; ushort* dst; int bid, nb;
  if (blk < 2048) { src = x; dst = Xbf; bid = blk; nb = 2048; }
  else            { src = W; dst = Wbf; bid = blk - 2048; nb = 128; }
  size_t base = (size_t)bid * 256 + threadIdx.x;
  size_t stride = (size_t)nb * 256;
  f32x4 a[4], b[4];
  #pragma unroll
  for (int it = 0; it < 4; ++it) {
    size_t i = base + (size_t)it * stride;
    a[it] = ((const f32x4*)src)[2 * i];
    b[it] = ((const f32x4*)src)[2 * i + 1];
  }
  #pragma unroll
  for (int it = 0; it < 4; ++it) {
    size_t i = base + (size_t)it * stride;
    ushort8 o;
    #pragma unroll
    for (int e = 0; e < 4; ++e) { o[e] = f2bf(a[it][e]); o[4 + e] = f2bf(b[it][e]); }
    ((ushort8*)dst)[i] = o;
  }
}

// ---------------- K2: 256x256 8-phase bf16 MFMA GEMM (T2+T3+T4+T5) ---------------
// (byte-identical main loop to rounds 4/5 — verified schedule; do not touch)
#define SBAR() do { asm volatile("" ::: "memory"); __builtin_amdgcn_s_barrier(); asm volatile("" ::: "memory"); } while (0)
#define LGKM0() asm volatile("s_waitcnt lgkmcnt(0)" ::: "memory")

#define RD_A(ABASE, MH)                                                            \
  { _Pragma("unroll") for (int mi_ = 0; mi_ < 4; ++mi_) {                          \
      int row_ = wr * 128 + (MH) * 64 + mi_ * 16 + fr;                             \
      const char* rp_ = (const char*)(ABASE) + row_ * 128;                         \
      _Pragma("unroll") for (int kk_ = 0; kk_ < 2; ++kk_) {                        \
        int slot_ = kk_ * 4 + kg;                                                  \
        areg[mi_][kk_] = *(const short8*)(rp_ + (((slot_ ^ (row_ & 7)) << 4)));    \
      } } }

#define RD_B(DST, BBASE, NH)                                                       \
  { _Pragma("unroll") for (int ni_ = 0; ni_ < 2; ++ni_) {                          \
      int row_ = wn * 64 + (NH) * 32 + ni_ * 16 + fr;                              \
      const char* rp_ = (const char*)(BBASE) + row_ * 128;                         \
      _Pragma("unroll") for (int kk_ = 0; kk_ < 2; ++kk_) {                        \
        int slot_ = kk_ * 4 + kg;                                                  \
        DST[ni_][kk_] = *(const short8*)(rp_ + (((slot_ ^ (row_ & 7)) << 4)));     \
      } } }

#define MF(MH, NH, BV)                                                             \
  { _Pragma("unroll") for (int mi_ = 0; mi_ < 4; ++mi_)                            \
      _Pragma("unroll") for (int ni_ = 0; ni_ < 2; ++ni_) {                        \
        acc[(MH)*4+mi_][(NH)*2+ni_] = __builtin_amdgcn_mfma_f32_16x16x32_bf16(     \
            areg[mi_][0], BV[ni_][0], acc[(MH)*4+mi_][(NH)*2+ni_], 0, 0, 0);       \
        acc[(MH)*4+mi_][(NH)*2+ni_] = __builtin_amdgcn_mfma_f32_16x16x32_bf16(     \
            areg[mi_][1], BV[ni_][1], acc[(MH)*4+mi_][(NH)*2+ni_], 0, 0, 0); } }

#define STAGE(LDSHALF, GROW, TTI)                                                  \
  { const ushort* g_ = (GROW) + (size_t)(wid * 16 + rl) * DM + (TTI) * 64 + sl * 8;\
    gload16(g_,          (LDSHALF) + wid * 1024);                                  \
    gload16(g_ + 8 * DM, (LDSHALF) + wid * 1024 + 512); }

__global__ __launch_bounds__(512, 2) void gemm_bias(const ushort* __restrict__ Xb,
                                                    const ushort* __restrict__ Wb,
                                                    const float* __restrict__ bias,
                                                    ushort* __restrict__ Yb,
                                                    float2* __restrict__ rowpart) {
  extern __shared__ ushort lds[];
  ushort* A0 = lds;
  ushort* B0 = lds + 16384;
  ushort* A1 = lds + 32768;
  ushort* B1 = lds + 49152;

  int wg = blockIdx.x;                        // 256 blocks = (64 bm) x (4 bn)
  int swz = (wg & 7) * 32 + (wg >> 3);        // XCD swizzle (256 % 8 == 0)
  int bm = swz >> 2, bn = swz & 3;
  int tid = threadIdx.x;
  int lane = tid & 63, wid = tid >> 6;        // 8 waves
  int wr = wid >> 2, wn = wid & 3;            // 2M x 4N
  int fr = lane & 15, kg = lane >> 4;
  int rl = lane >> 3, sl = (lane & 7) ^ rl;   // pre-swizzled global source

  const ushort* XgT = Xb + (size_t)(bm * 256) * DM;
  const ushort* XgB = XgT + (size_t)128 * DM;
  const ushort* WgT = Wb + (size_t)(bn * 256) * DM;
  const ushort* WgX = WgT + (size_t)128 * DM;

  f32x4 acc[8][4];
  #pragma unroll
  for (int i = 0; i < 8; ++i)
    #pragma unroll
    for (int j = 0; j < 4; ++j) acc[i][j] = (f32x4){0.f, 0.f, 0.f, 0.f};
  short8 areg[4][2], bt[2][2], bb[2][2];

  STAGE(A0,         XgT, 0);
  STAGE(A0 + 8192,  XgB, 0);
  STAGE(B0,         WgT, 0);
  STAGE(B0 + 8192,  WgX, 0);
  STAGE(B1,         WgT, 1);
  STAGE(B1 + 8192,  WgX, 1);
  asm volatile("s_waitcnt vmcnt(4)" ::: "memory");
  SBAR();

  #pragma unroll 1
  for (int t = 0; t < 8; ++t) {
    int o = 2 * t + 1, n0 = 2 * t + 2, n1 = 2 * t + 3;
    bool stg = (t < 7);
    RD_A(A0, 0); RD_B(bt, B0, 0);
    STAGE(A1, XgT, o);
    SBAR(); LGKM0();
    __builtin_amdgcn_s_setprio(1); MF(0, 0, bt); __builtin_amdgcn_s_setprio(0);
    SBAR();
    RD_B(bb, B0, 1);
    STAGE(A1 + 8192, XgB, o);
    SBAR(); LGKM0();
    __builtin_amdgcn_s_setprio(1); MF(0, 1, bb); __builtin_amdgcn_s_setprio(0);
    SBAR();
    RD_A(A0, 1);
    if (stg) STAGE(B0, WgT, n0);
    SBAR(); LGKM0();
    __builtin_amdgcn_s_setprio(1); MF(1, 1, bb); __builtin_amdgcn_s_setprio(0);
    SBAR();
    if (stg) {
      STAGE(B0 + 8192, WgX, n0);
      asm volatile("s_waitcnt vmcnt(4)" ::: "memory");
    } else {
      asm volatile("s_waitcnt vmcnt(0)" ::: "memory");
    }
    SBAR(); LGKM0();
    __builtin_amdgcn_s_setprio(1); MF(1, 0, bt); __builtin_amdgcn_s_setprio(0);
    SBAR();
    RD_A(A1, 0); RD_B(bt, B1, 0);
    if (stg) STAGE(A0, XgT, n0);
    SBAR(); LGKM0();
    __builtin_amdgcn_s_setprio(1); MF(0, 0, bt); __builtin_amdgcn_s_setprio(0);
    SBAR();
    RD_B(bb, B1, 1);
    if (stg) STAGE(A0 + 8192, XgB, n0);
    SBAR(); LGKM0();
    __builtin_amdgcn_s_setprio(1); MF(0, 1, bb); __builtin_amdgcn_s_setprio(0);
    SBAR();
    RD_A(A1, 1);
    if (stg) STAGE(B1, WgT, n1);
    SBAR(); LGKM0();
    __builtin_amdgcn_s_setprio(1); MF(1, 1, bb); __builtin_amdgcn_s_setprio(0);
    SBAR();
    if (stg) {
      STAGE(B1 + 8192, WgX, n1);
      asm volatile("s_waitcnt vmcnt(4)" ::: "memory");
    } else {
      asm volatile("s_waitcnt vmcnt(0)" ::: "memory");
    }
    SBAR(); LGKM0();
    __builtin_amdgcn_s_setprio(1); MF(1, 0, bt); __builtin_amdgcn_s_setprio(0);
    SBAR();
  }

  asm volatile("s_waitcnt vmcnt(0) lgkmcnt(0)" ::: "memory");
  __syncthreads();
  float* lsS = (float*)lds;
  float* lsQ = lsS + 1024;
  int fq = lane >> 4;
  float bv[4];
  #pragma unroll
  for (int ni = 0; ni < 4; ++ni) bv[ni] = bias[bn * 256 + wn * 64 + ni * 16 + fr];
  #pragma unroll
  for (int mi = 0; mi < 8; ++mi) {
    float rs_[4] = {0.f, 0.f, 0.f, 0.f}, rq_[4] = {0.f, 0.f, 0.f, 0.f};
    #pragma unroll
    for (int ni = 0; ni < 4; ++ni) {
      int gcol = bn * 256 + wn * 64 + ni * 16 + fr;
      #pragma unroll
      for (int j = 0; j < 4; ++j) {
        float v = acc[mi][ni][j] + bv[ni];
        int grow = bm * 256 + wr * 128 + mi * 16 + fq * 4 + j;
        Yb[(size_t)grow * DM + gcol] = f2bf(v);
        rs_[j] += v; rq_[j] += v * v;
      }
    }
    #pragma unroll
    for (int d = 1; d < 16; d <<= 1)
      #pragma unroll
      for (int j = 0; j < 4; ++j) {
        rs_[j] += __shfl_xor(rs_[j], d);
        rq_[j] += __shfl_xor(rq_[j], d);
      }
    if (fr == 0) {
      #pragma unroll
      for (int j = 0; j < 4; ++j) {
        int r = wr * 128 + mi * 16 + fq * 4 + j;
        lsS[wn * 256 + r] = rs_[j];
        lsQ[wn * 256 + r] = rq_[j];
      }
    }
  }
  __syncthreads();
  if (tid < 256) {
    float s = lsS[tid] + lsS[256 + tid] + lsS[512 + tid] + lsS[768 + tid];
    float q = lsQ[tid] + lsQ[256 + tid] + lsQ[512 + tid] + lsQ[768 + tid];
    rowpart[((size_t)(bm * 256 + tid)) * 4 + bn] = make_float2(s, q);
  }
}

// ---------------- helper: per-row LN stats from rowpart --------------------------
__device__ __forceinline__ void row_stats(const float2* __restrict__ rowpart,
                                          int grow, float& mu_, float& rs_) {
  float s = 0.f, q = 0.f;
  #pragma unroll
  for (int n = 0; n < 4; ++n) { float2 p = rowpart[(size_t)grow * 4 + n]; s += p.x; q += p.y; }
  mu_ = s * (1.f / DM);
  float v = q * (1.f / DM) - mu_ * mu_;
  rs_ = rsqrtf(v + 1e-5f);
}

// ---------------- K6: per-chunk sums of xln (2 channels/thread, inline stats) ----
__global__ __launch_bounds__(256) void chunksum(const ushort* __restrict__ ybf,
                                                const float2* __restrict__ rowpart,
                                                const float* __restrict__ gamma,
                                                const float* __restrict__ beta,
                                                float* __restrict__ partial) {
  int blk = blockIdx.x;                      // 8b x 16c x 2mg = 256
  int b = blk >> 5, c = (blk >> 1) & 15, mg = blk & 1;
  int tid = threadIdx.x;
  int m2 = mg * 512 + tid * 2;
  int bb = b * L_SEQ, cs = c * CL;
  __shared__ float muL[CL], rsL[CL];
  if (tid < CL) row_stats(rowpart, bb + cs + tid, muL[tid], rsL[tid]);
  __syncthreads();
  float g0 = gamma[m2], g1 = gamma[m2 + 1], be0 = beta[m2], be1 = beta[m2 + 1];
  float s0 = 0.f, s1 = 0.f;
  const ushort* base = ybf + (size_t)(bb + cs) * DM + m2;
  #pragma unroll 8
  for (int t = 0; t < CL; ++t) {
    uint32_t v = *(const uint32_t*)(base + (size_t)t * DM);
    float f0 = bf2f((ushort)v), f1 = bf2f((ushort)(v >> 16));
    float r = rsL[t], mu_ = muL[t];
    s0 += (f0 - mu_) * r * g0 + be0;
    s1 += (f1 - mu_) * r * g1 + be1;
  }
  *(float2*)&partial[((size_t)(b * NC + c)) * DM + m2] = make_float2(s0, s1);
}

// ---------------- K8: fused kgen + LN + FIR(8) + cumsum + residual ---------------
__global__ __launch_bounds__(256) void ssm2(const ushort* __restrict__ ybf,
                                            const float2* __restrict__ rowpart,
                                            const float* __restrict__ gamma,
                                            const float* __restrict__ beta,
                                            const float* __restrict__ A_re,
                                            const float* __restrict__ A_im,
                                            const float* __restrict__ B_re,
                                            const float* __restrict__ B_im,
                                            const float* __restrict__ C_re,
                                            const float* __restrict__ C_im,
                                            const float* __restrict__ D_re,
                                            const float* __restrict__ partial,
                                            float* __restrict__ Out) {
  int blk = blockIdx.x;                      // 8b x 16c x 4mg = 512
  int b = blk >> 6, c = (blk >> 2) & 15, mg = blk & 3;
  int tid = threadIdx.x;
  int m = mg * 256 + tid;
  int bb = b * L_SEQ, cs = c * CL;

  __shared__ float muL[CL + TT], rsL[CL + TT];   // rows cs-TT .. cs+CL-1
  __shared__ float PrT[TT][64], PiT[TT][64];     // A^s * B_n
  if (tid < 64) {
    float ar = A_re[tid], ai = A_im[tid];
    float br = B_re[tid], bi = B_im[tid];
    float pr = 1.f, pi = 0.f;
    #pragma unroll
    for (int s = 0; s < TT; ++s) {
      PrT[s][tid] = pr * br - pi * bi;
      PiT[s][tid] = pr * bi + pi * br;
      float npr = pr * ar - pi * ai;
      pi = pr * ai + pi * ar;
      pr = npr;
    }
  }
  for (int r = tid; r < CL + TT; r += 256) {
    int row = cs - TT + r;
    if (row >= 0) row_stats(rowpart, bb + row, muL[r], rsL[r]);
    else { muL[r] = 0.f; rsL[r] = 0.f; }
  }
  __syncthreads();

  // inline kgen: kh[s] = sum_n PrT[s][n]*C_re[m][n] - PiT[s][n]*C_im[m][n]
  float kh[TT];
  #pragma unroll
  for (int s = 0; s < TT; ++s) kh[s] = 0.f;
  {
    const float* cr = C_re + (size_t)m * 64;
    const float* ci = C_im + (size_t)m * 64;
    for (int n = 0; n < 64; ++n) {
      float crv = cr[n], civ = ci[n];
      #pragma unroll
      for (int s = 0; s < TT; ++s) kh[s] += PrT[s][n] * crv - PiT[s][n] * civ;
    }
  }

  float g = gamma[m], be = beta[m], dre = D_re[m];

  // inline exclusive scan over chunk partials
  float run = 0.f;
  for (int cc = 0; cc < c; ++cc) run += partial[((size_t)(b * NC + cc)) * DM + m];

  float P[TT], A[32];
  if (c == 0) {
    #pragma unroll
    for (int i = 0; i < TT; ++i) P[i] = 0.f;
  } else {
    #pragma unroll
    for (int i = 0; i < TT; ++i) {
      float v = bf2f(ybf[(size_t)(bb + cs - TT + i) * DM + m]);
      P[i] = (v - muL[i]) * rsL[i] * g + be;
    }
  }
  #pragma unroll
  for (int i = 0; i < 32; ++i) {
    float v = bf2f(ybf[(size_t)(bb + cs + i) * DM + m]);
    A[i] = (v - muL[TT + i]) * rsL[TT + i] * g + be;
  }

  #pragma unroll 1
  for (int j = 0; j < CL / 32; ++j) {
    float B[32];
    if (j < CL / 32 - 1) {
      int tb = (j + 1) * 32;
      #pragma unroll
      for (int i = 0; i < 32; ++i) {
        float v = bf2f(ybf[(size_t)(bb + cs + tb + i) * DM + m]);
        B[i] = (v - muL[TT + tb + i]) * rsL[TT + tb + i] * g + be;
      }
    }
    #pragma unroll
    for (int i = 0; i < 32; ++i) {
      float fir = 0.f;
      #pragma unroll
      for (int s = 0; s < TT; ++s) {
        float xv = (i - s >= 0) ? A[i - s] : P[TT + i - s];
        fir += kh[s] * xv;
      }
      run += A[i];
      Out[(size_t)(bb + cs + j * 32 + i) * DM + m] = A[i] + fir + dre * run;
    }
    #pragma unroll
    for (int i = 0; i < TT; ++i) P[i] = A[32 - TT + i];
    #pragma unroll
    for (int i = 0; i < 32; ++i) A[i] = B[i];
  }
}

extern "C" void kernel_launch(void* const* d_in, const int* in_sizes, int n_in,
                              void* d_out, int out_size, void* d_ws, size_t ws_size,
                              hipStream_t stream) {
  const float* x     = (const float*)d_in[0];
  const float* W     = (const float*)d_in[1];
  const float* b_in  = (const float*)d_in[2];
  const float* gamma = (const float*)d_in[3];
  const float* beta  = (const float*)d_in[4];
  const float* A_re  = (const float*)d_in[5];
  const float* A_im  = (const float*)d_in[6];
  const float* B_re  = (const float*)d_in[7];
  const float* B_im  = (const float*)d_in[8];
  const float* C_re  = (const float*)d_in[9];
  const float* C_im  = (const float*)d_in[10];
  const float* D_re  = (const float*)d_in[11];
  // d_in[12] = D_im: dead — reference keeps only Re(conv)

  char* ws = (char*)d_ws;
  ushort* Wbf     = (ushort*)(ws + 0);                   // 2MB
  ushort* ybf     = (ushort*)(ws + 2097152);             // 32MB
  float2* rowpart = (float2*)(ws + 35651584);            // 512KB
  float*  partial = (float*)(ws + 36175872);             // 512KB

  ushort* Xbf = (ushort*)d_out;        // d_out as scratch; dead after gemm
  float*  out = (float*)d_out;

  (void)hipFuncSetAttribute((const void*)gemm_bias,
                            hipFuncAttributeMaxDynamicSharedMemorySize, 131072);

  cvt_stream<<<2176, 256, 0, stream>>>(x, Xbf, W, Wbf);
  gemm_bias<<<256, 512, 131072, stream>>>(Xbf, Wbf, b_in, ybf, rowpart);
  chunksum<<<256, 256, 0, stream>>>(ybf, rowpart, gamma, beta, partial);
  ssm2<<<512, 256, 0, stream>>>(ybf, rowpart, gamma, beta,
                                A_re, A_im, B_re, B_im, C_re, C_im, D_re,
                                partial, out);
}